// Round 3
// baseline (1143.826 us; speedup 1.0000x reference)
//
#include <hip/hip_runtime.h>

#define DD 128

typedef __attribute__((ext_vector_type(8))) short bh8;       // 8 bf16 (as i16 bits)
typedef __attribute__((ext_vector_type(8))) unsigned short us8;
typedef __attribute__((ext_vector_type(4))) float f4;
typedef unsigned int u32;

// ---------------- CSR build (shared) ----------------

__global__ __launch_bounds__(256) void init_counts_k(int* cn, int* ce, int N, int E, int NE) {
  int g = blockIdx.x * blockDim.x + threadIdx.x;
  if (g < NE) ce[g] = (g >= E) ? 1 : 0;
  if (g < N)  cn[g] = 1;
}

__global__ __launch_bounds__(256) void hist_k(const int* __restrict__ ni, const int* __restrict__ ei,
                                              int* cn, int* ce, int nnz) {
  int stride = gridDim.x * blockDim.x;
  for (int j = blockIdx.x * blockDim.x + threadIdx.x; j < nnz; j += stride) {
    atomicAdd(&cn[ni[j]], 1);
    atomicAdd(&ce[ei[j]], 1);
  }
}

__global__ __launch_bounds__(1024) void exscan2_k(const int* __restrict__ cn, int* offs_n, int N,
                                                  const int* __restrict__ ce, int* offs_e, int NE) {
  const int* cnt = blockIdx.x ? ce : cn;
  int* offs = blockIdx.x ? offs_e : offs_n;
  int n = blockIdx.x ? NE : N;
  __shared__ int sums[1024];
  __shared__ int carry;
  const int tid = threadIdx.x;
  if (tid == 0) carry = 0;
  __syncthreads();
  const int PER = 8;
  const int CH = 1024 * PER;
  for (int base = 0; base < n; base += CH) {
    int i0 = base + tid * PER;
    int v[PER]; int s = 0;
    #pragma unroll
    for (int j = 0; j < PER; ++j) { int i = i0 + j; int t = (i < n) ? cnt[i] : 0; v[j] = t; s += t; }
    sums[tid] = s;
    __syncthreads();
    for (int off = 1; off < 1024; off <<= 1) {
      int t = (tid >= off) ? sums[tid - off] : 0;
      __syncthreads();
      sums[tid] += t;
      __syncthreads();
    }
    int excl = sums[tid] - s + carry;
    #pragma unroll
    for (int j = 0; j < PER; ++j) { int i = i0 + j; if (i < n) offs[i] = excl; excl += v[j]; }
    __syncthreads();
    if (tid == 0) carry += sums[1023];
    __syncthreads();
  }
  if (tid == 0) offs[n] = carry;
}

// self entries + inverse degrees + bucket cursor init (new path)
__global__ __launch_bounds__(256) void fill_self2_k(int* listN, int* listE,
                                                    const int* __restrict__ offs_n, const int* __restrict__ offs_e,
                                                    float* Dn_inv, float* De_inv,
                                                    int* cur_be, int* cur_bn,
                                                    int N, int E, int NE, int NBE, int NBN) {
  int g = blockIdx.x * blockDim.x + threadIdx.x;
  if (g < NE) {
    int b = offs_e[g], e = offs_e[g + 1];
    De_inv[g] = (e > b) ? 1.0f / (float)(e - b) : 0.0f;
    if (g >= E) listE[b] = g - E;
  }
  if (g < N) {
    int b = offs_n[g], e = offs_n[g + 1];
    Dn_inv[g] = (e > b) ? 1.0f / (float)(e - b) : 0.0f;
    listN[b] = E + g;
  }
  if (g < NBE) cur_be[g] = offs_e[g << 5];
  if (g < NBN) cur_bn[g] = offs_n[g << 5];
}

// bin incidences by destination bucket (32 ids/bucket); payload packed (local_id<<17 | value)
__global__ __launch_bounds__(256) void partition_k(const int* __restrict__ ni, const int* __restrict__ ei,
                                                   int* cur_be, int* cur_bn,
                                                   u32* __restrict__ SE, u32* __restrict__ SN, int nnz) {
  int stride = gridDim.x * blockDim.x;
  for (int j = blockIdx.x * blockDim.x + threadIdx.x; j < nnz; j += stride) {
    int n = ni[j], e = ei[j];
    int pe = atomicAdd(&cur_be[e >> 5], 1);
    SE[pe] = ((u32)(e & 31) << 17) | (u32)n;
    int pn = atomicAdd(&cur_bn[n >> 5], 1);
    SN[pn] = ((u32)(n & 31) << 17) | (u32)e;
  }
}

// within-bucket scatter; LDS cursors (selfFirst: reserve slot 0 of each segment for self entry)
template<int SELF>
__global__ __launch_bounds__(256) void scatter_k(const u32* __restrict__ S, const int* __restrict__ offs,
                                                 const int* __restrict__ cur_b_final,
                                                 int* __restrict__ list, int nIds) {
  __shared__ int cur[32];
  int b = blockIdx.x;
  int i0 = b << 5;
  int tid = threadIdx.x;
  if (tid < 32) {
    int id = i0 + tid;
    cur[tid] = (id < nIds) ? offs[id] + SELF : 0;
  }
  __syncthreads();
  int beg = offs[i0];
  int end = cur_b_final[b];
  for (int i = beg + tid; i < end; i += 256) {
    u32 v = S[i];
    int l = v >> 17;
    int val = (int)(v & 0x1FFFFu);
    int pos = atomicAdd(&cur[l], 1);
    list[pos] = val;
  }
}

// ---------------- legacy CSR (fallback) ----------------

__global__ __launch_bounds__(256) void fill_self_k(int* cur_n, int* cur_e, int* listN, int* listE,
                                                   const int* __restrict__ offs_n, const int* __restrict__ offs_e,
                                                   float* Dn_inv, float* De_inv,
                                                   int N, int E, int NE) {
  int g = blockIdx.x * blockDim.x + threadIdx.x;
  if (g < NE) {
    int b = offs_e[g], e = offs_e[g + 1];
    De_inv[g] = (e > b) ? 1.0f / (float)(e - b) : 0.0f;
    if (g < E) cur_e[g] = b;
    else { listE[b] = g - E; cur_e[g] = b + 1; }
  }
  if (g < N) {
    int b = offs_n[g], e = offs_n[g + 1];
    Dn_inv[g] = (e > b) ? 1.0f / (float)(e - b) : 0.0f;
    listN[b] = E + g; cur_n[g] = b + 1;
  }
}

__global__ __launch_bounds__(256) void fill_nnz_k(const int* __restrict__ ni, const int* __restrict__ ei,
                                                  int* cur_n, int* cur_e, int* listN, int* listE, int nnz) {
  int stride = gridDim.x * blockDim.x;
  for (int j = blockIdx.x * blockDim.x + threadIdx.x; j < nnz; j += stride) {
    int n = ni[j], e = ei[j];
    int pn = atomicAdd(&cur_n[n], 1); listN[pn] = e;
    int pe = atomicAdd(&cur_e[e], 1); listE[pe] = n;
  }
}

// ---------------- gather ----------------

template<int MODE>
__global__ __launch_bounds__(256) void gather_k(const float* __restrict__ src,
                                                const int* __restrict__ offs, const int* __restrict__ list,
                                                const float* __restrict__ scale, const float* __restrict__ bias,
                                                const float* __restrict__ alphap, float* __restrict__ dst,
                                                float* __restrict__ dst2, int dst2_rows, int nrows) {
  const int wave = threadIdx.x >> 6, lane = threadIdx.x & 63;
  const int row = blockIdx.x * 4 + wave;
  if (row >= nrows) return;
  const int c2 = lane * 2;
  const int beg = offs[row], end = offs[row + 1];
  float2 a0 = {0.f, 0.f}, a1 = {0.f, 0.f}, a2 = {0.f, 0.f}, a3 = {0.f, 0.f};
  int i = beg;
  for (; i + 3 < end; i += 4) {
    int s0 = list[i], s1 = list[i + 1], s2 = list[i + 2], s3 = list[i + 3];
    float2 v0 = *(const float2*)&src[(size_t)s0 * DD + c2];
    float2 v1 = *(const float2*)&src[(size_t)s1 * DD + c2];
    float2 v2 = *(const float2*)&src[(size_t)s2 * DD + c2];
    float2 v3 = *(const float2*)&src[(size_t)s3 * DD + c2];
    a0.x += v0.x; a0.y += v0.y; a1.x += v1.x; a1.y += v1.y;
    a2.x += v2.x; a2.y += v2.y; a3.x += v3.x; a3.y += v3.y;
  }
  for (; i < end; ++i) {
    float2 v = *(const float2*)&src[(size_t)list[i] * DD + c2];
    a0.x += v.x; a0.y += v.y;
  }
  float sc = scale[row];
  float vx = sc * ((a0.x + a1.x) + (a2.x + a3.x));
  float vy = sc * ((a0.y + a1.y) + (a2.y + a3.y));
  if constexpr (MODE == 1) {
    float2 bt = *(const float2*)&bias[c2];
    float al = *alphap;
    vx += bt.x; vy += bt.y;
    vx = (vx >= 0.f) ? vx : al * vx;
    vy = (vy >= 0.f) ? vy : al * vy;
  }
  float2 o = {vx, vy};
  *(float2*)&dst[(size_t)row * DD + c2] = o;
  if constexpr (MODE == 1) {
    if (dst2 && row < dst2_rows) *(float2*)&dst2[(size_t)row * DD + c2] = o;
  }
}

// ---------------- weight prep ----------------

struct WPtrs { const float* p[16]; };

__global__ __launch_bounds__(256) void prep_w_k(WPtrs wp, char* dst) {
  int m = blockIdx.x >> 3, s = blockIdx.x & 7;
  const float* W = wp.p[m];
  int t = threadIdx.x;
  int n = t & 127;
  int k0 = s * 16 + (t >> 7) * 8;
  us8 vhi, vlo;
  #pragma unroll
  for (int j = 0; j < 8; ++j) {
    float x = W[(size_t)(k0 + j) * DD + n];
    u32 ux = __builtin_bit_cast(u32, x);
    float hf = __builtin_bit_cast(float, ux & 0xFFFF0000u);
    float l = x - hf;
    vhi[j] = (unsigned short)(ux >> 16);
    vlo[j] = (unsigned short)(__builtin_bit_cast(u32, l) >> 16);
  }
  char* base = dst + (size_t)m * 65536;
  int byte = n * 256 + k0 * 2;
  byte ^= (n & 7) << 4;
  *(us8*)(base + byte) = vhi;
  *(us8*)(base + 32768 + byte) = vlo;
}

// ---------------- MFMA GEMM machinery ----------------

__device__ __forceinline__ void stage_w(const char* gsrc, char* lds, int tid) {
  int wave = tid >> 6, lane = tid & 63;
  #pragma unroll
  for (int i = 0; i < 16; ++i) {
    int off = (wave * 16 + i) * 1024;
    __builtin_amdgcn_global_load_lds(
        (const __attribute__((address_space(1))) u32*)(gsrc + off + lane * 16),
        (__attribute__((address_space(3))) u32*)(lds + off), 16, 0, 0);
  }
}

__device__ __forceinline__ void split8(const float vs[8], bh8& hi, bh8& lo) {
  #pragma unroll
  for (int j = 0; j < 8; ++j) {
    u32 u = __builtin_bit_cast(u32, vs[j]);
    float hf = __builtin_bit_cast(float, u & 0xFFFF0000u);
    float l = vs[j] - hf;
    hi[j] = (short)(u >> 16);
    lo[j] = (short)(__builtin_bit_cast(u32, l) >> 16);
  }
}

__device__ __forceinline__ void mk_afrag(const float* rowp, int koff, bh8& hi, bh8& lo) {
  float4 v0 = *(const float4*)(rowp + koff);
  float4 v1 = *(const float4*)(rowp + koff + 4);
  float vs[8] = {v0.x, v0.y, v0.z, v0.w, v1.x, v1.y, v1.z, v1.w};
  split8(vs, hi, lo);
}

struct AFrag { bh8 hi[4]; bh8 lo[4]; };

__device__ __forceinline__ void load_afrag(const float* __restrict__ A, int rbase, int nrows, int lane, AFrag& f) {
  int r = rbase + (lane & 15);
  if (r >= nrows) r = nrows - 1;
  const float* rowp = A + (size_t)r * DD;
  const int koff0 = (lane >> 4) * 8;
  #pragma unroll
  for (int ks = 0; ks < 4; ++ks) mk_afrag(rowp, ks * 32 + koff0, f.hi[ks], f.lo[ks]);
}

__device__ __forceinline__ void mfma_ks(const bh8& ahi, const bh8& alo, const char* Wl,
                                        int ks, int lane, f4 acc[8]) {
  const int koff0 = (lane >> 4) * 8;
  const int k2 = (ks * 32 + koff0) * 2;
  #pragma unroll
  for (int cb = 0; cb < 8; ++cb) {
    int n = cb * 16 + (lane & 15);
    int byte = (n * 256 + k2) ^ ((n & 7) << 4);
    bh8 bhiF = *(const bh8*)(Wl + byte);
    bh8 bloF = *(const bh8*)(Wl + 32768 + byte);
    acc[cb] = __builtin_amdgcn_mfma_f32_16x16x32_bf16(ahi, bhiF, acc[cb], 0, 0, 0);
    acc[cb] = __builtin_amdgcn_mfma_f32_16x16x32_bf16(ahi, bloF, acc[cb], 0, 0, 0);
    acc[cb] = __builtin_amdgcn_mfma_f32_16x16x32_bf16(alo, bhiF, acc[cb], 0, 0, 0);
  }
}

__device__ __forceinline__ void mfma_pass(const float* __restrict__ A, const char* Wl,
                                          int rbase, int nrows, int lane, f4 acc[8]) {
  int r = rbase + (lane & 15);
  if (r >= nrows) r = nrows - 1;
  const float* rowp = A + (size_t)r * DD;
  const int koff0 = (lane >> 4) * 8;
  #pragma unroll
  for (int ks = 0; ks < 4; ++ks) {
    bh8 ahi, alo;
    mk_afrag(rowp, ks * 32 + koff0, ahi, alo);
    mfma_ks(ahi, alo, Wl, ks, lane, acc);
  }
}

__device__ __forceinline__ void mfma_pass_frag(const AFrag& f, const char* Wl, int lane, f4 acc[8]) {
  #pragma unroll
  for (int ks = 0; ks < 4; ++ks) mfma_ks(f.hi[ks], f.lo[ks], Wl, ks, lane, acc);
}

template<int MODE>
__device__ __forceinline__ void epilogue(f4 acc[8], const float* bias, const float* alphap,
                                         float* out, int rbase, int nrows, int lane) {
  float al = 0.f;
  if constexpr (MODE == 1) al = *alphap;
  const int cidx = lane & 15;
  int rq = rbase + (lane >> 4) * 4;
  float b8[8];
  if constexpr (MODE == 1) {
    #pragma unroll
    for (int cb = 0; cb < 8; ++cb) b8[cb] = bias[cb * 16 + cidx];
  }
  #pragma unroll
  for (int q = 0; q < 4; ++q) {
    int row = rq + q;
    if (row < nrows) {
      float* op = out + (size_t)row * DD + cidx;
      #pragma unroll
      for (int cb = 0; cb < 8; ++cb) {
        float v = acc[cb][q];
        if constexpr (MODE == 1) { v += b8[cb]; v = (v >= 0.f) ? v : al * v; }
        op[cb * 16] = v;
      }
    }
  }
}

// ---------------- GEMM kernels ----------------

template<int MODE>
__global__ __launch_bounds__(256, 2) void gemm_mfma_k(const float* __restrict__ A, const char* __restrict__ Wprep,
                                                      const float* __restrict__ bias, const float* __restrict__ alphap,
                                                      float* __restrict__ out, int nrows) {
  __shared__ char Wl[65536];
  stage_w(Wprep, Wl, threadIdx.x);
  __syncthreads();
  const int wave = threadIdx.x >> 6, lane = threadIdx.x & 63;
  const int rbase = blockIdx.x * 64 + wave * 16;
  f4 acc[8];
  #pragma unroll
  for (int cb = 0; cb < 8; ++cb) acc[cb] = {0.f, 0.f, 0.f, 0.f};
  mfma_pass(A, Wl, rbase, nrows, lane, acc);
  epilogue<MODE>(acc, bias, alphap, out, rbase, nrows, lane);
}

__global__ __launch_bounds__(256, 2) void gemm_mfma_dual_k(const float* __restrict__ A1, const char* __restrict__ W1,
                                                           const float* __restrict__ A2, const char* __restrict__ W2,
                                                           const float* __restrict__ bias, const float* __restrict__ alphap,
                                                           float* __restrict__ out, int nrows) {
  __shared__ char Wl[65536];
  stage_w(W1, Wl, threadIdx.x);
  __syncthreads();
  const int wave = threadIdx.x >> 6, lane = threadIdx.x & 63;
  const int rbase = blockIdx.x * 64 + wave * 16;
  f4 acc[8];
  #pragma unroll
  for (int cb = 0; cb < 8; ++cb) acc[cb] = {0.f, 0.f, 0.f, 0.f};
  mfma_pass(A1, Wl, rbase, nrows, lane, acc);
  __syncthreads();
  stage_w(W2, Wl, threadIdx.x);
  __syncthreads();
  mfma_pass(A2, Wl, rbase, nrows, lane, acc);
  epilogue<1>(acc, bias, alphap, out, rbase, nrows, lane);
}

// fused: out = prelu(A@W1 + b) @ W2   (intermediate in LDS T-tile)
__global__ __launch_bounds__(256, 1) void gemm_fuse2_k(const float* __restrict__ A, const char* __restrict__ W1,
                                                       const float* __restrict__ bias, const float* __restrict__ alphap,
                                                       const char* __restrict__ W2,
                                                       float* __restrict__ out, int nrows) {
  __shared__ char Wl[65536];
  __shared__ float T[64][132];   // +4 pad: 2-way-free banks for rd & wr
  stage_w(W1, Wl, threadIdx.x);
  __syncthreads();
  const int wave = threadIdx.x >> 6, lane = threadIdx.x & 63;
  const int rbase = blockIdx.x * 64 + wave * 16;
  f4 acc[8];
  #pragma unroll
  for (int cb = 0; cb < 8; ++cb) acc[cb] = {0.f, 0.f, 0.f, 0.f};
  mfma_pass(A, Wl, rbase, nrows, lane, acc);
  // prelu + bias -> T
  {
    float al = *alphap;
    const int cidx = lane & 15;
    int rl = wave * 16 + (lane >> 4) * 4;
    #pragma unroll
    for (int cb = 0; cb < 8; ++cb) {
      float b = bias[cb * 16 + cidx];
      #pragma unroll
      for (int q = 0; q < 4; ++q) {
        float v = acc[cb][q] + b;
        v = (v >= 0.f) ? v : al * v;
        T[rl + q][cb * 16 + cidx] = v;
      }
    }
  }
  __syncthreads();
  stage_w(W2, Wl, threadIdx.x);
  __syncthreads();
  // second GEMM: A-frags from T
  #pragma unroll
  for (int cb = 0; cb < 8; ++cb) acc[cb] = {0.f, 0.f, 0.f, 0.f};
  {
    const int rl = wave * 16 + (lane & 15);
    const int koff0 = (lane >> 4) * 8;
    #pragma unroll
    for (int ks = 0; ks < 4; ++ks) {
      int k = ks * 32 + koff0;
      float4 v0 = *(const float4*)&T[rl][k];
      float4 v1 = *(const float4*)&T[rl][k + 4];
      float vs[8] = {v0.x, v0.y, v0.z, v0.w, v1.x, v1.y, v1.z, v1.w};
      bh8 ahi, alo;
      split8(vs, ahi, alo);
      mfma_ks(ahi, alo, Wl, ks, lane, acc);
    }
  }
  epilogue<0>(acc, nullptr, nullptr, out, rbase, nrows, lane);
}

// encoder final: out_n = prelu(agg@W + b); also writes nn1 half (row stride 256, col offset coff)
__global__ __launch_bounds__(256, 2) void gemm_enc_final_k(const float* __restrict__ A, const char* __restrict__ Wprep,
                                                           const float* __restrict__ bias, const float* __restrict__ alphap,
                                                           float* __restrict__ out_n, float* __restrict__ nn1, int coff,
                                                           int nrows) {
  __shared__ char Wl[65536];
  stage_w(Wprep, Wl, threadIdx.x);
  __syncthreads();
  const int wave = threadIdx.x >> 6, lane = threadIdx.x & 63;
  const int rbase = blockIdx.x * 64 + wave * 16;
  f4 acc[8];
  #pragma unroll
  for (int cb = 0; cb < 8; ++cb) acc[cb] = {0.f, 0.f, 0.f, 0.f};
  mfma_pass(A, Wl, rbase, nrows, lane, acc);
  float al = *alphap;
  const int cidx = lane & 15;
  int rq = rbase + (lane >> 4) * 4;
  float b8[8];
  #pragma unroll
  for (int cb = 0; cb < 8; ++cb) b8[cb] = bias[cb * 16 + cidx];
  #pragma unroll
  for (int q = 0; q < 4; ++q) {
    int row = rq + q;
    if (row < nrows) {
      float* op = out_n + (size_t)row * DD + cidx;
      float* op2 = nn1 + (size_t)row * 256 + coff + cidx;
      #pragma unroll
      for (int cb = 0; cb < 8; ++cb) {
        float v = acc[cb][q] + b8[cb];
        v = (v >= 0.f) ? v : al * v;
        op[cb * 16] = v;
        op2[cb * 16] = v;
      }
    }
  }
}

// decoder layer-0 pair: o1 = prelu(x0@WxA + agg@WeA + bA); o2 = prelu(x0@WxB + agg@WeB + bB)
__global__ __launch_bounds__(256, 2) void dec_pair_l0_k(const float* __restrict__ x0, const float* __restrict__ agg,
                                                        const char* WxA, const char* WeA, const float* bA,
                                                        const char* WxB, const char* WeB, const float* bB,
                                                        const float* __restrict__ alphap,
                                                        float* __restrict__ o1, float* __restrict__ o2, int nrows) {
  __shared__ char Wl[65536];
  const int wave = threadIdx.x >> 6, lane = threadIdx.x & 63;
  const int rbase = blockIdx.x * 64 + wave * 16;
  AFrag fx, fa;
  load_afrag(x0, rbase, nrows, lane, fx);
  load_afrag(agg, rbase, nrows, lane, fa);
  f4 acc[8];
  stage_w(WxA, Wl, threadIdx.x);
  __syncthreads();
  #pragma unroll
  for (int cb = 0; cb < 8; ++cb) acc[cb] = {0.f, 0.f, 0.f, 0.f};
  mfma_pass_frag(fx, Wl, lane, acc);
  __syncthreads();
  stage_w(WeA, Wl, threadIdx.x);
  __syncthreads();
  mfma_pass_frag(fa, Wl, lane, acc);
  epilogue<1>(acc, bA, alphap, o1, rbase, nrows, lane);
  __syncthreads();
  stage_w(WxB, Wl, threadIdx.x);
  __syncthreads();
  #pragma unroll
  for (int cb = 0; cb < 8; ++cb) acc[cb] = {0.f, 0.f, 0.f, 0.f};
  mfma_pass_frag(fx, Wl, lane, acc);
  __syncthreads();
  stage_w(WeB, Wl, threadIdx.x);
  __syncthreads();
  mfma_pass_frag(fa, Wl, lane, acc);
  epilogue<1>(acc, bB, alphap, o2, rbase, nrows, lane);
}

// decoder layer-1 pair: o1 = prelu(t0@WxA + agg@WeA + bA); o2 = prelu(t1@WxB + agg@WeB + bB)
__global__ __launch_bounds__(256, 2) void dec_pair_l1_k(const float* __restrict__ t0, const float* __restrict__ t1,
                                                        const float* __restrict__ agg,
                                                        const char* WxA, const char* WeA, const float* bA,
                                                        const char* WxB, const char* WeB, const float* bB,
                                                        const float* __restrict__ alphap,
                                                        float* __restrict__ o1, float* __restrict__ o2, int nrows) {
  __shared__ char Wl[65536];
  const int wave = threadIdx.x >> 6, lane = threadIdx.x & 63;
  const int rbase = blockIdx.x * 64 + wave * 16;
  AFrag f0, f1, fa;
  load_afrag(t0, rbase, nrows, lane, f0);
  load_afrag(t1, rbase, nrows, lane, f1);
  load_afrag(agg, rbase, nrows, lane, fa);
  f4 acc[8];
  stage_w(WxA, Wl, threadIdx.x);
  __syncthreads();
  #pragma unroll
  for (int cb = 0; cb < 8; ++cb) acc[cb] = {0.f, 0.f, 0.f, 0.f};
  mfma_pass_frag(f0, Wl, lane, acc);
  __syncthreads();
  stage_w(WeA, Wl, threadIdx.x);
  __syncthreads();
  mfma_pass_frag(fa, Wl, lane, acc);
  epilogue<1>(acc, bA, alphap, o1, rbase, nrows, lane);
  __syncthreads();
  stage_w(WxB, Wl, threadIdx.x);
  __syncthreads();
  #pragma unroll
  for (int cb = 0; cb < 8; ++cb) acc[cb] = {0.f, 0.f, 0.f, 0.f};
  mfma_pass_frag(f1, Wl, lane, acc);
  __syncthreads();
  stage_w(WeB, Wl, threadIdx.x);
  __syncthreads();
  mfma_pass_frag(fa, Wl, lane, acc);
  epilogue<1>(acc, bB, alphap, o2, rbase, nrows, lane);
}

// ---------------- copies (legacy path) ----------------

__global__ __launch_bounds__(256) void copy4_k(const float4* __restrict__ src, float4* __restrict__ dst, int n4) {
  int stride = gridDim.x * blockDim.x;
  for (int i = blockIdx.x * blockDim.x + threadIdx.x; i < n4; i += stride) dst[i] = src[i];
}

__global__ __launch_bounds__(256) void concat_k(const float4* __restrict__ n1, const float4* __restrict__ n2,
                                                float4* __restrict__ nn1, int N) {
  int stride = gridDim.x * blockDim.x;
  int tot = N * 32;
  for (int g = blockIdx.x * blockDim.x + threadIdx.x; g < tot; g += stride) {
    int r = g >> 5, q = g & 31;
    nn1[(size_t)r * 64 + q] = n1[g];
    nn1[(size_t)r * 64 + 32 + q] = n2[g];
  }
}

// ---------------- host ----------------

extern "C" void kernel_launch(void* const* d_in, const int* in_sizes, int n_in,
                              void* d_out, int out_size, void* d_ws, size_t ws_size,
                              hipStream_t stream) {
  const float* x        = (const float*)d_in[0];
  const float* xx       = (const float*)d_in[1];
  const int*   node_idx = (const int*)d_in[2];
  const int*   edge_idx = (const int*)d_in[3];
  const float* alphap   = (const float*)d_in[6];
  const float* e1_Wn2e  = (const float*)d_in[7];
  const float* e1_bn2e  = (const float*)d_in[8];
  const float* e1_We2n  = (const float*)d_in[9];
  const float* e1_be2n  = (const float*)d_in[10];
  const float* e2_Wn2e  = (const float*)d_in[11];
  const float* e2_bn2e  = (const float*)d_in[12];
  const float* e2_We2n  = (const float*)d_in[13];
  const float* e2_be2n  = (const float*)d_in[14];
  const float* d1_We    = (const float*)d_in[15];
  const float* d1_Wx    = (const float*)d_in[16];
  const float* d1_b     = (const float*)d_in[17];
  const float* d2_We    = (const float*)d_in[18];
  const float* d2_Wx    = (const float*)d_in[19];
  const float* d2_b     = (const float*)d_in[20];

  const int N   = in_sizes[0] / DD;
  const int NNZ = in_sizes[2];
  const int E   = (out_size - 1024 * N) / 256;
  const int NE  = E + N;
  const long long M = (long long)NNZ + N;
  const int NBE = (E + 31) >> 5;
  const int NBN = (N + 31) >> 5;

  // ---- d_out slot map ----
  float* out  = (float*)d_out;
  float* nn1  = out;
  float* n1   = out + (size_t)N * 256;
  float* e1o  = n1 + (size_t)N * DD;
  float* n2   = e1o + (size_t)E * DD;
  float* e2o  = n2 + (size_t)N * DD;
  float* x11  = e2o + (size_t)E * DD;
  float* x21  = x11 + (size_t)N * DD;
  float* x12  = x21 + (size_t)N * DD;
  float* x22  = x12 + (size_t)N * DD;

  // ---- workspace carve (big path) ----
  size_t off = 0;
  char* w0 = (char*)d_ws;
  auto carve = [&](size_t bytes) -> void* {
    void* p = (void*)(w0 + off);
    off += (bytes + 255) & ~(size_t)255;
    return p;
  };
  int* cn      = (int*)carve((size_t)N * 4);
  int* ce      = (int*)carve((size_t)NE * 4);
  int* offs_n  = (int*)carve((size_t)(N + 1) * 4);
  int* offs_e  = (int*)carve((size_t)(NE + 1) * 4);
  int* listN   = (int*)carve((size_t)M * 4);
  int* listE   = (int*)carve((size_t)M * 4);
  float* Dn_inv = (float*)carve((size_t)N * 4);
  float* De_inv = (float*)carve((size_t)NE * 4);
  float* e_full = (float*)carve((size_t)NE * DD * 4);
  char* Wprep  = (char*)carve((size_t)16 * 65536);
  int* cur_be  = (int*)carve((size_t)NBE * 4);
  int* cur_bn  = (int*)carve((size_t)NBN * 4);
  u32* SE      = (u32*)carve((size_t)NNZ * 4);
  u32* SN      = (u32*)carve((size_t)M * 4);
  float* agg1  = (float*)carve((size_t)N * DD * 4);
  float* agg2  = (float*)carve((size_t)N * DD * 4);
  float* t0    = (float*)carve((size_t)N * DD * 4);
  float* t1    = (float*)carve((size_t)N * DD * 4);
  int* cur_n   = (int*)carve((size_t)N * 4);   // legacy only
  int* cur_e   = (int*)carve((size_t)NE * 4);  // legacy only
  const bool big = off <= ws_size;

  // ---- weight prep table ----
  WPtrs wp;
  wp.p[0] = e1_Wn2e;  wp.p[1] = e1_Wn2e + DD * DD;
  wp.p[2] = e1_We2n;  wp.p[3] = e1_We2n + DD * DD;
  wp.p[4] = e2_Wn2e;  wp.p[5] = e2_Wn2e + DD * DD;
  wp.p[6] = e2_We2n;  wp.p[7] = e2_We2n + DD * DD;
  wp.p[8] = d1_We;    wp.p[9] = d1_We + DD * DD;
  wp.p[10] = d1_Wx;   wp.p[11] = d1_Wx + DD * DD;
  wp.p[12] = d2_We;   wp.p[13] = d2_We + DD * DD;
  wp.p[14] = d2_Wx;   wp.p[15] = d2_Wx + DD * DD;
  auto WP = [&](int i) -> const char* { return Wprep + (size_t)i * 65536; };

  const int thr = 256;
  const int gNE = (NE + thr - 1) / thr;
  int gNNZ = (NNZ + thr - 1) / thr; if (gNNZ > 2048) gNNZ = 2048;
  const int gGemm = (N + 63) / 64;
  const int gGatE = (NE + 3) / 4;
  const int gGatN = (N + 3) / 4;

  prep_w_k<<<128, 256, 0, stream>>>(wp, Wprep);
  init_counts_k<<<gNE, thr, 0, stream>>>(cn, ce, N, E, NE);
  hist_k<<<gNNZ, thr, 0, stream>>>(node_idx, edge_idx, cn, ce, NNZ);
  exscan2_k<<<2, 1024, 0, stream>>>(cn, offs_n, N, ce, offs_e, NE);

  if (big) {
    fill_self2_k<<<gNE, thr, 0, stream>>>(listN, listE, offs_n, offs_e, Dn_inv, De_inv,
                                          cur_be, cur_bn, N, E, NE, NBE, NBN);
    partition_k<<<gNNZ, thr, 0, stream>>>(node_idx, edge_idx, cur_be, cur_bn, SE, SN, NNZ);
    scatter_k<0><<<NBE, 256, 0, stream>>>(SE, offs_e, cur_be, listE, E);
    scatter_k<1><<<NBN, 256, 0, stream>>>(SN, offs_n, cur_bn, listN, N);

    auto encoder = [&](const float* X0, int wi, const float* bn2e, const float* be2n,
                       float* nOut, int coff, float* aggOut, float* eOut) {
      gemm_mfma_k<0><<<gGemm, 256, 0, stream>>>(X0, WP(wi), nullptr, nullptr, t0, N);
      gather_k<1><<<gGatE, 256, 0, stream>>>(t0, offs_e, listE, De_inv, bn2e, alphap, e_full, nullptr, 0, NE);
      gather_k<0><<<gGatN, 256, 0, stream>>>(e_full, offs_n, listN, Dn_inv, nullptr, nullptr, t1, nullptr, 0, N);
      gemm_fuse2_k<<<gGemm, 256, 0, stream>>>(t1, WP(wi + 2), be2n, alphap, WP(wi + 1), t0, N);
      gather_k<1><<<gGatE, 256, 0, stream>>>(t0, offs_e, listE, De_inv, bn2e + DD, alphap, e_full, eOut, E, NE);
      gather_k<0><<<gGatN, 256, 0, stream>>>(e_full, offs_n, listN, Dn_inv, nullptr, nullptr, aggOut, nullptr, 0, N);
      gemm_enc_final_k<<<gGemm, 256, 0, stream>>>(aggOut, WP(wi + 3), be2n + DD, alphap, nOut, nn1, coff, N);
    };

    encoder(x,  0, e1_bn2e, e1_be2n, n1, 0,   agg1, e1o);
    encoder(xx, 4, e2_bn2e, e2_be2n, n2, 128, agg2, e2o);

    // decoder pairs: (n1,agg1) -> x11 (d1), x22 (d2);  (n2,agg2) -> x12 (d1), x21 (d2)
    dec_pair_l0_k<<<gGemm, 256, 0, stream>>>(n1, agg1, WP(10), WP(8), d1_b, WP(14), WP(12), d2_b,
                                             alphap, t0, t1, N);
    dec_pair_l1_k<<<gGemm, 256, 0, stream>>>(t0, t1, agg1, WP(11), WP(9), d1_b + DD, WP(15), WP(13), d2_b + DD,
                                             alphap, x11, x22, N);
    dec_pair_l0_k<<<gGemm, 256, 0, stream>>>(n2, agg2, WP(10), WP(8), d1_b, WP(14), WP(12), d2_b,
                                             alphap, t0, t1, N);
    dec_pair_l1_k<<<gGemm, 256, 0, stream>>>(t0, t1, agg2, WP(11), WP(9), d1_b + DD, WP(15), WP(13), d2_b + DD,
                                             alphap, x12, x21, N);
  } else {
    // ---- legacy (round-2) path: scratch aliased into d_out ----
    float* scrA = nn1;
    float* scrB = nn1 + (size_t)N * DD;
    float* agg1l = x22;
    float* agg2l = x21;
    fill_self_k<<<gNE, thr, 0, stream>>>(cur_n, cur_e, listN, listE, offs_n, offs_e, Dn_inv, De_inv, N, E, NE);
    fill_nnz_k<<<gNNZ, thr, 0, stream>>>(node_idx, edge_idx, cur_n, cur_e, listN, listE, NNZ);

    auto encoder = [&](const float* X0, int wi, const float* bn2e, const float* be2n,
                       float* nOut, float* aggOut, float* eOut) {
      gemm_mfma_k<0><<<gGemm, 256, 0, stream>>>(X0, WP(wi), nullptr, nullptr, scrA, N);
      gather_k<1><<<gGatE, 256, 0, stream>>>(scrA, offs_e, listE, De_inv, bn2e, alphap, e_full, nullptr, 0, NE);
      gather_k<0><<<gGatN, 256, 0, stream>>>(e_full, offs_n, listN, Dn_inv, nullptr, nullptr, scrA, nullptr, 0, N);
      gemm_mfma_k<1><<<gGemm, 256, 0, stream>>>(scrA, WP(wi + 2), be2n, alphap, scrB, N);
      gemm_mfma_k<0><<<gGemm, 256, 0, stream>>>(scrB, WP(wi + 1), nullptr, nullptr, scrA, N);
      gather_k<1><<<gGatE, 256, 0, stream>>>(scrA, offs_e, listE, De_inv, bn2e + DD, alphap, e_full, eOut, E, NE);
      gather_k<0><<<gGatN, 256, 0, stream>>>(e_full, offs_n, listN, Dn_inv, nullptr, nullptr, aggOut, nullptr, 0, N);
      gemm_mfma_k<1><<<gGemm, 256, 0, stream>>>(aggOut, WP(wi + 3), be2n + DD, alphap, nOut, N);
    };

    encoder(x,  0, e1_bn2e, e1_be2n, n1, agg1l, e1o);
    encoder(xx, 4, e2_bn2e, e2_be2n, n2, agg2l, e2o);

    auto decoder = [&](const float* x0, const float* agg, int we0, int wx0,
                       const float* b, float* outSlot, bool direct) {
      float* tgt = direct ? outSlot : scrA;
      gemm_mfma_dual_k<<<gGemm, 256, 0, stream>>>(x0, WP(wx0), agg, WP(we0), b, alphap, scrB, N);
      gemm_mfma_dual_k<<<gGemm, 256, 0, stream>>>(scrB, WP(wx0 + 1), agg, WP(we0 + 1), b + DD, alphap, tgt, N);
      if (!direct) {
        int n4 = N * 32;
        int g = (n4 + 255) / 256; if (g > 2048) g = 2048;
        copy4_k<<<g, 256, 0, stream>>>((const float4*)scrA, (float4*)outSlot, n4);
      }
    };

    decoder(n1, agg1l, 8, 10, d1_b, x11, true);
    decoder(n2, agg2l, 8, 10, d1_b, x12, true);
    decoder(n1, agg1l, 12, 14, d2_b, x22, false);
    decoder(n2, agg2l, 12, 14, d2_b, x21, false);

    int tot = N * 32;
    int g = (tot + 255) / 256; if (g > 4096) g = 4096;
    concat_k<<<g, 256, 0, stream>>>((const float4*)n1, (const float4*)n2, (float4*)nn1, N);
  }
}

// Round 4
// 1021.882 us; speedup vs baseline: 1.1193x; 1.1193x over previous
//
#include <hip/hip_runtime.h>

#define DD 128

typedef __attribute__((ext_vector_type(8))) short bh8;       // 8 bf16 (as i16 bits)
typedef __attribute__((ext_vector_type(8))) unsigned short us8;
typedef __attribute__((ext_vector_type(4))) float f4;
typedef unsigned int u32;

// ================= CSR build =================

__global__ __launch_bounds__(256) void init_counts_k(int* cn, int* ce, int N, int E, int NE) {
  int g = blockIdx.x * blockDim.x + threadIdx.x;
  if (g < NE) ce[g] = (g >= E) ? 1 : 0;
  if (g < N)  cn[g] = 1;
}

__global__ __launch_bounds__(256) void hist_k(const int* __restrict__ ni, const int* __restrict__ ei,
                                              int* cn, int* ce, int nnz) {
  int stride = gridDim.x * blockDim.x;
  for (int j = blockIdx.x * blockDim.x + threadIdx.x; j < nnz; j += stride) {
    atomicAdd(&cn[ni[j]], 1);
    atomicAdd(&ce[ei[j]], 1);
  }
}

__global__ __launch_bounds__(1024) void exscan2_k(const int* __restrict__ cn, int* offs_n, int N,
                                                  const int* __restrict__ ce, int* offs_e, int NE) {
  const int* cnt = blockIdx.x ? ce : cn;
  int* offs = blockIdx.x ? offs_e : offs_n;
  int n = blockIdx.x ? NE : N;
  __shared__ int sums[1024];
  __shared__ int carry;
  const int tid = threadIdx.x;
  if (tid == 0) carry = 0;
  __syncthreads();
  const int PER = 8;
  const int CH = 1024 * PER;
  for (int base = 0; base < n; base += CH) {
    int i0 = base + tid * PER;
    int v[PER]; int s = 0;
    #pragma unroll
    for (int j = 0; j < PER; ++j) { int i = i0 + j; int t = (i < n) ? cnt[i] : 0; v[j] = t; s += t; }
    sums[tid] = s;
    __syncthreads();
    for (int off = 1; off < 1024; off <<= 1) {
      int t = (tid >= off) ? sums[tid - off] : 0;
      __syncthreads();
      sums[tid] += t;
      __syncthreads();
    }
    int excl = sums[tid] - s + carry;
    #pragma unroll
    for (int j = 0; j < PER; ++j) { int i = i0 + j; if (i < n) offs[i] = excl; excl += v[j]; }
    __syncthreads();
    if (tid == 0) carry += sums[1023];
    __syncthreads();
  }
  if (tid == 0) offs[n] = carry;
}

// self entries + inverse degrees + per-(bucket,xcd) staging cursor init
__global__ __launch_bounds__(256) void fill_self2_k(int* listN, int* listE,
                                                    const int* __restrict__ offs_n, const int* __restrict__ offs_e,
                                                    float* Dn_inv, float* De_inv,
                                                    int* cur_be, int* cur_bn,
                                                    int N, int E, int NE, int NBE, int NBN) {
  int g = blockIdx.x * blockDim.x + threadIdx.x;
  if (g < NE) {
    int b = offs_e[g], e = offs_e[g + 1];
    De_inv[g] = (e > b) ? 1.0f / (float)(e - b) : 0.0f;
    if (g >= E) listE[b] = g - E;
  }
  if (g < N) {
    int b = offs_n[g], e = offs_n[g + 1];
    Dn_inv[g] = (e > b) ? 1.0f / (float)(e - b) : 0.0f;
    listN[b] = E + g;
  }
  if (g < NBE) {
    int r1 = (g + 1) * 32; if (r1 > E) r1 = E;
    int o0 = offs_e[g * 32], o1 = offs_e[r1];
    int C = o1 - o0, base = 8 * o0;
    #pragma unroll
    for (int k = 0; k < 8; ++k) cur_be[g * 8 + k] = base + k * C;
  }
  if (g < NBN) {
    int r1 = (g + 1) * 32; if (r1 > N) r1 = N;
    int o0 = offs_n[g * 32], o1 = offs_n[r1];
    int C = o1 - o0, base = 8 * o0;
    #pragma unroll
    for (int k = 0; k < 8; ++k) cur_bn[g * 8 + k] = base + k * C;
  }
}

// XCD-local binning: each block appends to its own XCD's sub-region per bucket
__global__ __launch_bounds__(256) void partition2_k(const int* __restrict__ ni, const int* __restrict__ ei,
                                                    int* cur_be, int* cur_bn,
                                                    u32* __restrict__ SE, u32* __restrict__ SN, int nnz) {
  int xcd;
  asm volatile("s_getreg_b32 %0, hwreg(HW_REG_XCC_ID)" : "=s"(xcd));
  xcd &= 7;
  int stride = gridDim.x * blockDim.x;
  for (int j = blockIdx.x * blockDim.x + threadIdx.x; j < nnz; j += stride) {
    int n = ni[j], e = ei[j];
    int pe = atomicAdd(&cur_be[(e >> 5) * 8 + xcd], 1);
    SE[pe] = ((u32)(e & 31) << 17) | (u32)n;
    int pn = atomicAdd(&cur_bn[(n >> 5) * 8 + xcd], 1);
    SN[pn] = ((u32)(n & 31) << 17) | (u32)e;
  }
}

// within-bucket exact scatter; one workgroup owns one bucket's CSR range
template<int SELF>
__global__ __launch_bounds__(256) void scatter2_k(const u32* __restrict__ S, const int* __restrict__ offs,
                                                  const int* __restrict__ cur_b,
                                                  int* __restrict__ list, int nRows) {
  __shared__ int cur[32];
  const int b = blockIdx.x;
  const int i0 = b << 5;
  const int tid = threadIdx.x;
  if (tid < 32) {
    int row = i0 + tid;
    cur[tid] = (row < nRows) ? offs[row] + SELF : 0;
  }
  __syncthreads();
  int r1 = i0 + 32; if (r1 > nRows) r1 = nRows;
  const int o0 = offs[i0];
  const int C = offs[r1] - o0;
  #pragma unroll 1
  for (int k = 0; k < 8; ++k) {
    int sbeg = 8 * o0 + k * C;
    int send = cur_b[b * 8 + k];
    for (int i = sbeg + tid; i < send; i += 256) {
      u32 v = S[i];
      int pos = atomicAdd(&cur[v >> 17], 1);
      list[pos] = (int)(v & 0x1FFFFu);
    }
  }
}

// ---- legacy fallback ----
__global__ __launch_bounds__(256) void fill_self_k(int* cur_n, int* cur_e, int* listN, int* listE,
                                                   const int* __restrict__ offs_n, const int* __restrict__ offs_e,
                                                   float* Dn_inv, float* De_inv,
                                                   int N, int E, int NE) {
  int g = blockIdx.x * blockDim.x + threadIdx.x;
  if (g < NE) {
    int b = offs_e[g], e = offs_e[g + 1];
    De_inv[g] = (e > b) ? 1.0f / (float)(e - b) : 0.0f;
    if (g < E) cur_e[g] = b;
    else { listE[b] = g - E; cur_e[g] = b + 1; }
  }
  if (g < N) {
    int b = offs_n[g], e = offs_n[g + 1];
    Dn_inv[g] = (e > b) ? 1.0f / (float)(e - b) : 0.0f;
    listN[b] = E + g; cur_n[g] = b + 1;
  }
}

__global__ __launch_bounds__(256) void fill_nnz_k(const int* __restrict__ ni, const int* __restrict__ ei,
                                                  int* cur_n, int* cur_e, int* listN, int* listE, int nnz) {
  int stride = gridDim.x * blockDim.x;
  for (int j = blockIdx.x * blockDim.x + threadIdx.x; j < nnz; j += stride) {
    int n = ni[j], e = ei[j];
    int pn = atomicAdd(&cur_n[n], 1); listN[pn] = e;
    int pe = atomicAdd(&cur_e[e], 1); listE[pe] = n;
  }
}

// ================= gather (width 256, 1 wave/row, float4 lanes) =================
// MODE 0: dst = scale[row] * sum
// MODE 1: dst = prelu(scale[row]*sum + bias[c]); optional split outputs d2a (cols<128), d2b (cols>=128) for row<d2rows
template<int MODE>
__global__ __launch_bounds__(256) void gather256_k(const float* __restrict__ src,
                                                   const int* __restrict__ offs, const int* __restrict__ list,
                                                   const float* __restrict__ scale,
                                                   const float* __restrict__ b1, const float* __restrict__ b2,
                                                   const float* __restrict__ alphap, float* __restrict__ dst,
                                                   float* __restrict__ d2a, float* __restrict__ d2b, int d2rows,
                                                   int nrows) {
  const int wave = threadIdx.x >> 6, lane = threadIdx.x & 63;
  const int row = blockIdx.x * 4 + wave;
  if (row >= nrows) return;
  const int c = lane * 4;
  const int beg = offs[row], end = offs[row + 1];
  float4 a0 = {0,0,0,0}, a1 = {0,0,0,0}, a2 = {0,0,0,0}, a3 = {0,0,0,0};
  int i = beg;
  for (; i + 3 < end; i += 4) {
    int s0 = list[i], s1 = list[i + 1], s2 = list[i + 2], s3 = list[i + 3];
    float4 v0 = *(const float4*)&src[(size_t)s0 * 256 + c];
    float4 v1 = *(const float4*)&src[(size_t)s1 * 256 + c];
    float4 v2 = *(const float4*)&src[(size_t)s2 * 256 + c];
    float4 v3 = *(const float4*)&src[(size_t)s3 * 256 + c];
    a0.x += v0.x; a0.y += v0.y; a0.z += v0.z; a0.w += v0.w;
    a1.x += v1.x; a1.y += v1.y; a1.z += v1.z; a1.w += v1.w;
    a2.x += v2.x; a2.y += v2.y; a2.z += v2.z; a2.w += v2.w;
    a3.x += v3.x; a3.y += v3.y; a3.z += v3.z; a3.w += v3.w;
  }
  for (; i < end; ++i) {
    float4 v = *(const float4*)&src[(size_t)list[i] * 256 + c];
    a0.x += v.x; a0.y += v.y; a0.z += v.z; a0.w += v.w;
  }
  float sc = scale[row];
  float4 o;
  o.x = sc * ((a0.x + a1.x) + (a2.x + a3.x));
  o.y = sc * ((a0.y + a1.y) + (a2.y + a3.y));
  o.z = sc * ((a0.z + a1.z) + (a2.z + a3.z));
  o.w = sc * ((a0.w + a1.w) + (a2.w + a3.w));
  if constexpr (MODE == 1) {
    const float* bp = (c < 128) ? (b1 + c) : (b2 + c - 128);
    float4 bt = *(const float4*)bp;
    float al = *alphap;
    o.x += bt.x; o.y += bt.y; o.z += bt.z; o.w += bt.w;
    o.x = (o.x >= 0.f) ? o.x : al * o.x;
    o.y = (o.y >= 0.f) ? o.y : al * o.y;
    o.z = (o.z >= 0.f) ? o.z : al * o.z;
    o.w = (o.w >= 0.f) ? o.w : al * o.w;
  }
  *(float4*)&dst[(size_t)row * 256 + c] = o;
  if constexpr (MODE == 1) {
    if (row < d2rows) {
      if (c < 128) *(float4*)&d2a[(size_t)row * DD + c] = o;
      else         *(float4*)&d2b[(size_t)row * DD + c - 128] = o;
    }
  }
}

// ================= weight prep =================

struct WPtrs { const float* p[16]; };

__global__ __launch_bounds__(256) void prep_w_k(WPtrs wp, char* dst) {
  int m = blockIdx.x >> 3, s = blockIdx.x & 7;
  const float* W = wp.p[m];
  int t = threadIdx.x;
  int n = t & 127;
  int k0 = s * 16 + (t >> 7) * 8;
  us8 vhi, vlo;
  #pragma unroll
  for (int j = 0; j < 8; ++j) {
    float x = W[(size_t)(k0 + j) * DD + n];
    u32 ux = __builtin_bit_cast(u32, x);
    float hf = __builtin_bit_cast(float, ux & 0xFFFF0000u);
    float l = x - hf;
    vhi[j] = (unsigned short)(ux >> 16);
    vlo[j] = (unsigned short)(__builtin_bit_cast(u32, l) >> 16);
  }
  char* base = dst + (size_t)m * 65536;
  int byte = n * 256 + k0 * 2;
  byte ^= (n & 7) << 4;
  *(us8*)(base + byte) = vhi;
  *(us8*)(base + 32768 + byte) = vlo;
}

// ================= MFMA machinery =================

__device__ __forceinline__ void stage_w(const char* gsrc, char* lds, int tid) {
  int wave = tid >> 6, lane = tid & 63;
  #pragma unroll
  for (int i = 0; i < 16; ++i) {
    int off = (wave * 16 + i) * 1024;
    __builtin_amdgcn_global_load_lds(
        (const __attribute__((address_space(1))) u32*)(gsrc + off + lane * 16),
        (__attribute__((address_space(3))) u32*)(lds + off), 16, 0, 0);
  }
}

__device__ __forceinline__ void split8(const float vs[8], bh8& hi, bh8& lo) {
  #pragma unroll
  for (int j = 0; j < 8; ++j) {
    u32 u = __builtin_bit_cast(u32, vs[j]);
    float hf = __builtin_bit_cast(float, u & 0xFFFF0000u);
    float l = vs[j] - hf;
    hi[j] = (short)(u >> 16);
    lo[j] = (short)(__builtin_bit_cast(u32, l) >> 16);
  }
}

__device__ __forceinline__ void mk_afrag(const float* rowp, int koff, bh8& hi, bh8& lo) {
  float4 v0 = *(const float4*)(rowp + koff);
  float4 v1 = *(const float4*)(rowp + koff + 4);
  float vs[8] = {v0.x, v0.y, v0.z, v0.w, v1.x, v1.y, v1.z, v1.w};
  split8(vs, hi, lo);
}

struct AFrag { bh8 hi[4]; bh8 lo[4]; };

__device__ __forceinline__ void load_afragS(const float* __restrict__ A, size_t astride, int acoff,
                                            int rbase, int nrows, int lane, AFrag& f) {
  int r = rbase + (lane & 15);
  if (r >= nrows) r = nrows - 1;
  const float* rowp = A + (size_t)r * astride + acoff;
  const int koff0 = (lane >> 4) * 8;
  #pragma unroll
  for (int ks = 0; ks < 4; ++ks) mk_afrag(rowp, ks * 32 + koff0, f.hi[ks], f.lo[ks]);
}

__device__ __forceinline__ void mfma_ks(const bh8& ahi, const bh8& alo, const char* Wl,
                                        int ks, int lane, f4 acc[8]) {
  const int koff0 = (lane >> 4) * 8;
  const int k2 = (ks * 32 + koff0) * 2;
  #pragma unroll
  for (int cb = 0; cb < 8; ++cb) {
    int n = cb * 16 + (lane & 15);
    int byte = (n * 256 + k2) ^ ((n & 7) << 4);
    bh8 bhiF = *(const bh8*)(Wl + byte);
    bh8 bloF = *(const bh8*)(Wl + 32768 + byte);
    acc[cb] = __builtin_amdgcn_mfma_f32_16x16x32_bf16(ahi, bhiF, acc[cb], 0, 0, 0);
    acc[cb] = __builtin_amdgcn_mfma_f32_16x16x32_bf16(ahi, bloF, acc[cb], 0, 0, 0);
    acc[cb] = __builtin_amdgcn_mfma_f32_16x16x32_bf16(alo, bhiF, acc[cb], 0, 0, 0);
  }
}

__device__ __forceinline__ void mfma_passS(const float* __restrict__ A, size_t astride, int acoff,
                                           const char* Wl, int rbase, int nrows, int lane, f4 acc[8]) {
  int r = rbase + (lane & 15);
  if (r >= nrows) r = nrows - 1;
  const float* rowp = A + (size_t)r * astride + acoff;
  const int koff0 = (lane >> 4) * 8;
  #pragma unroll
  for (int ks = 0; ks < 4; ++ks) {
    bh8 ahi, alo;
    mk_afrag(rowp, ks * 32 + koff0, ahi, alo);
    mfma_ks(ahi, alo, Wl, ks, lane, acc);
  }
}

__device__ __forceinline__ void mfma_pass_frag(const AFrag& f, const char* Wl, int lane, f4 acc[8]) {
  #pragma unroll
  for (int ks = 0; ks < 4; ++ks) mfma_ks(f.hi[ks], f.lo[ks], Wl, ks, lane, acc);
}

template<int MODE>
__device__ __forceinline__ void epilogueS(f4 acc[8], const float* bias, const float* alphap,
                                          float* out, size_t ostride, int ocoff,
                                          int rbase, int nrows, int lane) {
  float al = 0.f;
  if constexpr (MODE == 1) al = *alphap;
  const int cidx = lane & 15;
  int rq = rbase + (lane >> 4) * 4;
  float b8[8];
  if constexpr (MODE == 1) {
    #pragma unroll
    for (int cb = 0; cb < 8; ++cb) b8[cb] = bias[cb * 16 + cidx];
  }
  #pragma unroll
  for (int q = 0; q < 4; ++q) {
    int row = rq + q;
    if (row < nrows) {
      float* op = out + (size_t)row * ostride + ocoff + cidx;
      #pragma unroll
      for (int cb = 0; cb < 8; ++cb) {
        float v = acc[cb][q];
        if constexpr (MODE == 1) { v += b8[cb]; v = (v >= 0.f) ? v : al * v; }
        op[cb * 16] = v;
      }
    }
  }
}

#define ACC_ZERO(acc) { _Pragma("unroll") for (int cb = 0; cb < 8; ++cb) acc[cb] = {0.f, 0.f, 0.f, 0.f}; }

// ================= GEMM kernels =================

// out256 halves: h1 = A1@W1 (+act), h2 = A2@W2 (+act). A strided.
template<int MODE>
__global__ __launch_bounds__(256, 2) void gemm_halves_k(const float* __restrict__ A1, size_t as1, int ac1, const char* W1, const float* b1_,
                                                        const float* __restrict__ A2, size_t as2, int ac2, const char* W2, const float* b2_,
                                                        const float* __restrict__ alphap,
                                                        float* __restrict__ out, int nrows) {
  __shared__ char Wl[65536];
  const int wave = threadIdx.x >> 6, lane = threadIdx.x & 63;
  const int rbase = blockIdx.x * 64 + wave * 16;
  f4 acc[8];
  stage_w(W1, Wl, threadIdx.x);
  __syncthreads();
  ACC_ZERO(acc);
  mfma_passS(A1, as1, ac1, Wl, rbase, nrows, lane, acc);
  epilogueS<MODE>(acc, b1_, alphap, out, 256, 0, rbase, nrows, lane);
  __syncthreads();
  stage_w(W2, Wl, threadIdx.x);
  __syncthreads();
  ACC_ZERO(acc);
  mfma_passS(A2, as2, ac2, Wl, rbase, nrows, lane, acc);
  epilogueS<MODE>(acc, b2_, alphap, out, 256, 128, rbase, nrows, lane);
}

// encoder final: n1 = prelu(agg_h1@W1+b1), n2 = prelu(agg_h2@W2+b2); nn1 gets both halves
__global__ __launch_bounds__(256, 2) void enc_final_k(const float* __restrict__ agg, const char* W1, const float* b1_,
                                                      const char* W2, const float* b2_,
                                                      const float* __restrict__ alphap,
                                                      float* __restrict__ n1, float* __restrict__ n2,
                                                      float* __restrict__ nn1, int nrows) {
  __shared__ char Wl[65536];
  const int wave = threadIdx.x >> 6, lane = threadIdx.x & 63;
  const int rbase = blockIdx.x * 64 + wave * 16;
  const int cidx = lane & 15;
  f4 acc[8];
  float al = *alphap;
  #pragma unroll 1
  for (int h = 0; h < 2; ++h) {
    stage_w(h ? W2 : W1, Wl, threadIdx.x);
    __syncthreads();
    ACC_ZERO(acc);
    mfma_passS(agg, 256, h * 128, Wl, rbase, nrows, lane, acc);
    const float* bp = h ? b2_ : b1_;
    float* nout = h ? n2 : n1;
    float b8[8];
    #pragma unroll
    for (int cb = 0; cb < 8; ++cb) b8[cb] = bp[cb * 16 + cidx];
    int rq = rbase + (lane >> 4) * 4;
    #pragma unroll
    for (int q = 0; q < 4; ++q) {
      int row = rq + q;
      if (row < nrows) {
        float* op = nout + (size_t)row * DD + cidx;
        float* op2 = nn1 + (size_t)row * 256 + h * 128 + cidx;
        #pragma unroll
        for (int cb = 0; cb < 8; ++cb) {
          float v = acc[cb][q] + b8[cb];
          v = (v >= 0.f) ? v : al * v;
          op[cb * 16] = v;
          op2[cb * 16] = v;
        }
      }
    }
    __syncthreads();
  }
}

// decoder pair layer: o1 = prelu(xA@WxA + agg_h@WeA + bA); o2 = prelu(xB@WxB + agg_h@WeB + bB)
// (xA==xB for layer 0)
__global__ __launch_bounds__(256, 2) void dec_pair_k(const float* __restrict__ xA, const float* __restrict__ xB,
                                                     const float* __restrict__ agg, int acoff,
                                                     const char* WxA, const char* WeA, const float* bA,
                                                     const char* WxB, const char* WeB, const float* bB,
                                                     const float* __restrict__ alphap,
                                                     float* __restrict__ o1, float* __restrict__ o2, int nrows) {
  __shared__ char Wl[65536];
  const int wave = threadIdx.x >> 6, lane = threadIdx.x & 63;
  const int rbase = blockIdx.x * 64 + wave * 16;
  AFrag fa;
  load_afragS(agg, 256, acoff, rbase, nrows, lane, fa);
  f4 acc[8];
  stage_w(WxA, Wl, threadIdx.x);
  __syncthreads();
  ACC_ZERO(acc);
  mfma_passS(xA, DD, 0, Wl, rbase, nrows, lane, acc);
  __syncthreads();
  stage_w(WeA, Wl, threadIdx.x);
  __syncthreads();
  mfma_pass_frag(fa, Wl, lane, acc);
  epilogueS<1>(acc, bA, alphap, o1, DD, 0, rbase, nrows, lane);
  __syncthreads();
  stage_w(WxB, Wl, threadIdx.x);
  __syncthreads();
  ACC_ZERO(acc);
  mfma_passS(xB, DD, 0, Wl, rbase, nrows, lane, acc);
  __syncthreads();
  stage_w(WeB, Wl, threadIdx.x);
  __syncthreads();
  mfma_pass_frag(fa, Wl, lane, acc);
  epilogueS<1>(acc, bB, alphap, o2, DD, 0, rbase, nrows, lane);
}

// ================= host =================

extern "C" void kernel_launch(void* const* d_in, const int* in_sizes, int n_in,
                              void* d_out, int out_size, void* d_ws, size_t ws_size,
                              hipStream_t stream) {
  const float* x        = (const float*)d_in[0];
  const float* xx       = (const float*)d_in[1];
  const int*   node_idx = (const int*)d_in[2];
  const int*   edge_idx = (const int*)d_in[3];
  const float* alphap   = (const float*)d_in[6];
  const float* e1_Wn2e  = (const float*)d_in[7];
  const float* e1_bn2e  = (const float*)d_in[8];
  const float* e1_We2n  = (const float*)d_in[9];
  const float* e1_be2n  = (const float*)d_in[10];
  const float* e2_Wn2e  = (const float*)d_in[11];
  const float* e2_bn2e  = (const float*)d_in[12];
  const float* e2_We2n  = (const float*)d_in[13];
  const float* e2_be2n  = (const float*)d_in[14];
  const float* d1_We    = (const float*)d_in[15];
  const float* d1_Wx    = (const float*)d_in[16];
  const float* d1_b     = (const float*)d_in[17];
  const float* d2_We    = (const float*)d_in[18];
  const float* d2_Wx    = (const float*)d_in[19];
  const float* d2_b     = (const float*)d_in[20];

  const int N   = in_sizes[0] / DD;
  const int NNZ = in_sizes[2];
  const int E   = (out_size - 1024 * N) / 256;
  const int NE  = E + N;
  const long long M = (long long)NNZ + N;
  const int NBE = (E + 31) >> 5;
  const int NBN = (N + 31) >> 5;

  // ---- d_out slot map ----
  float* out  = (float*)d_out;
  float* nn1  = out;
  float* n1   = out + (size_t)N * 256;
  float* e1o  = n1 + (size_t)N * DD;
  float* n2   = e1o + (size_t)E * DD;
  float* e2o  = n2 + (size_t)N * DD;
  float* x11  = e2o + (size_t)E * DD;
  float* x21  = x11 + (size_t)N * DD;
  float* x12  = x21 + (size_t)N * DD;
  float* x22  = x12 + (size_t)N * DD;

  // ---- workspace carve ----
  size_t off = 0;
  char* w0 = (char*)d_ws;
  auto carve = [&](size_t bytes) -> void* {
    void* p = (void*)(w0 + off);
    off += (bytes + 255) & ~(size_t)255;
    return p;
  };
  int* cn      = (int*)carve((size_t)N * 4);
  int* ce      = (int*)carve((size_t)NE * 4);
  int* offs_n  = (int*)carve((size_t)(N + 1) * 4);
  int* offs_e  = (int*)carve((size_t)(NE + 1) * 4);
  int* listN   = (int*)carve((size_t)M * 4);
  int* listE   = (int*)carve((size_t)M * 4);
  float* Dn_inv = (float*)carve((size_t)N * 4);
  float* De_inv = (float*)carve((size_t)NE * 4);
  char* Wprep  = (char*)carve((size_t)16 * 65536);
  float* t0    = (float*)carve((size_t)N * 256 * 4);
  float* t1    = (float*)carve((size_t)N * 256 * 4);
  float* agg   = (float*)carve((size_t)N * 256 * 4);
  float* e_full = (float*)carve((size_t)NE * 256 * 4);
  size_t base_need = off;
  // staged-CSR extras
  int* cur_be  = (int*)carve((size_t)NBE * 8 * 4);
  int* cur_bn  = (int*)carve((size_t)NBN * 8 * 4);
  u32* SE      = (u32*)carve((size_t)NNZ * 8 * 4);
  u32* SN      = (u32*)carve((size_t)M * 8 * 4);
  size_t staged_need = off;
  int* cur_n   = (int*)cur_be;   // legacy aliases (only used if !staged)
  int* cur_e   = (int*)cur_bn;
  const bool staged = staged_need <= ws_size;
  // if even base doesn't fit we're out of luck; base ≈ 240MB, harness ws has been ~880MB
  (void)base_need;

  // ---- weight prep table ----
  WPtrs wp;
  wp.p[0] = e1_Wn2e;  wp.p[1] = e1_Wn2e + DD * DD;
  wp.p[2] = e1_We2n;  wp.p[3] = e1_We2n + DD * DD;
  wp.p[4] = e2_Wn2e;  wp.p[5] = e2_Wn2e + DD * DD;
  wp.p[6] = e2_We2n;  wp.p[7] = e2_We2n + DD * DD;
  wp.p[8] = d1_We;    wp.p[9] = d1_We + DD * DD;
  wp.p[10] = d1_Wx;   wp.p[11] = d1_Wx + DD * DD;
  wp.p[12] = d2_We;   wp.p[13] = d2_We + DD * DD;
  wp.p[14] = d2_Wx;   wp.p[15] = d2_Wx + DD * DD;
  auto WP = [&](int i) -> const char* { return Wprep + (size_t)i * 65536; };

  const int thr = 256;
  const int gNE = (NE + thr - 1) / thr;
  int gNNZ = (NNZ + thr - 1) / thr; if (gNNZ > 2048) gNNZ = 2048;
  const int gGemm = (N + 63) / 64;
  const int gGatE = (NE + 3) / 4;
  const int gGatN = (N + 3) / 4;

  prep_w_k<<<128, 256, 0, stream>>>(wp, Wprep);
  init_counts_k<<<gNE, thr, 0, stream>>>(cn, ce, N, E, NE);
  hist_k<<<gNNZ, thr, 0, stream>>>(node_idx, edge_idx, cn, ce, NNZ);
  exscan2_k<<<2, 1024, 0, stream>>>(cn, offs_n, N, ce, offs_e, NE);

  if (staged) {
    fill_self2_k<<<gNE, thr, 0, stream>>>(listN, listE, offs_n, offs_e, Dn_inv, De_inv,
                                          cur_be, cur_bn, N, E, NE, NBE, NBN);
    partition2_k<<<gNNZ, thr, 0, stream>>>(node_idx, edge_idx, cur_be, cur_bn, SE, SN, NNZ);
    scatter2_k<0><<<NBE, 256, 0, stream>>>(SE, offs_e, cur_be, listE, E);
    scatter2_k<1><<<NBN, 256, 0, stream>>>(SN, offs_n, cur_bn, listN, N);
  } else {
    fill_self_k<<<gNE, thr, 0, stream>>>(cur_n, cur_e, listN, listE, offs_n, offs_e, Dn_inv, De_inv, N, E, NE);
    fill_nnz_k<<<gNNZ, thr, 0, stream>>>(node_idx, edge_idx, cur_n, cur_e, listN, listE, NNZ);
  }

  // ---- fused dual-encoder (width-256 features: half1 = enc1, half2 = enc2) ----
  // L1: t0 = [x@Wn2e1_0 | xx@Wn2e2_0]
  gemm_halves_k<0><<<gGemm, 256, 0, stream>>>(x, DD, 0, WP(0), nullptr,
                                              xx, DD, 0, WP(4), nullptr, alphap, t0, N);
  // e(L1) = prelu(De * seg_e(t0) + bn2e_0)
  gather256_k<1><<<gGatE, 256, 0, stream>>>(t0, offs_e, listE, De_inv, e1_bn2e, e2_bn2e,
                                            alphap, e_full, nullptr, nullptr, 0, NE);
  // t1 = Dn * seg_n(e)
  gather256_k<0><<<gGatN, 256, 0, stream>>>(e_full, offs_n, listN, Dn_inv, nullptr, nullptr,
                                            alphap, t1, nullptr, nullptr, 0, N);
  // hidden = prelu(t1@We2n_0 + be2n_0)
  gemm_halves_k<1><<<gGemm, 256, 0, stream>>>(t1, 256, 0, WP(2), e1_be2n,
                                              t1, 256, 128, WP(6), e2_be2n, alphap, t0, N);
  // t1 = hidden@Wn2e_1
  gemm_halves_k<0><<<gGemm, 256, 0, stream>>>(t0, 256, 0, WP(1), nullptr,
                                              t0, 256, 128, WP(5), nullptr, alphap, t1, N);
  // e(L2) = prelu(De * seg_e(t1) + bn2e_1)  (+ writes e1o/e2o rows < E)
  gather256_k<1><<<gGatE, 256, 0, stream>>>(t1, offs_e, listE, De_inv, e1_bn2e + DD, e2_bn2e + DD,
                                            alphap, e_full, e1o, e2o, E, NE);
  // agg = Dn * seg_n(e)   (= [agg_e1 | agg_e2], shared by encoder-final and all decoders)
  gather256_k<0><<<gGatN, 256, 0, stream>>>(e_full, offs_n, listN, Dn_inv, nullptr, nullptr,
                                            alphap, agg, nullptr, nullptr, 0, N);
  // n1, n2, nn1
  enc_final_k<<<gGemm, 256, 0, stream>>>(agg, WP(3), e1_be2n + DD, WP(7), e2_be2n + DD,
                                         alphap, n1, n2, nn1, N);

  // ---- decoders (pairs share x0 and agg-half) ----
  float* dt0 = t0;                       // dense [N][128] scratch
  float* dt1 = t0 + (size_t)N * DD;
  // (n1, agg1): d1 -> x11, d2 -> x22
  dec_pair_k<<<gGemm, 256, 0, stream>>>(n1, n1, agg, 0, WP(10), WP(8), d1_b, WP(14), WP(12), d2_b,
                                        alphap, dt0, dt1, N);
  dec_pair_k<<<gGemm, 256, 0, stream>>>(dt0, dt1, agg, 0, WP(11), WP(9), d1_b + DD, WP(15), WP(13), d2_b + DD,
                                        alphap, x11, x22, N);
  // (n2, agg2): d1 -> x12, d2 -> x21
  dec_pair_k<<<gGemm, 256, 0, stream>>>(n2, n2, agg, 128, WP(10), WP(8), d1_b, WP(14), WP(12), d2_b,
                                        alphap, dt0, dt1, N);
  dec_pair_k<<<gGemm, 256, 0, stream>>>(dt0, dt1, agg, 128, WP(11), WP(9), d1_b + DD, WP(15), WP(13), d2_b + DD,
                                        alphap, x12, x21, N);
}